// Round 5
// baseline (78.908 us; speedup 1.0000x reference)
//
#include <hip/hip_runtime.h>
#include <hip/hip_bf16.h>
#include <math.h>

// Problem constants (from reference):
//   x: (b=8, t=16, c=64, h=56, w=56) f32   -> 25,690,112 elems
//   pos_embedding: (512, 16, 64) f32
//   W_qk: (64, 128) f32  (in, out) ; q = cols 0..63, k = cols 64..127
//   gamma, beta: (64,) f32
// out[b,t,c,f] = sum_j (softmax(q k^T * 0.125)[bc,t,j] + delta_tj) * x[b,j,c,f]
// where bc = b*64 + c, f = h*w = 3136.
//
// ws layout: s_ws = 512*16*64 floats (2 MB), attn_ws = 512*256 floats (0.5 MB)
// total 2.5 MB <= ws_size.

#define HW 3136            // 56*56
#define HW4 784            // HW/4
#define TSTRIDE4 50176     // 64*784, float4 stride between t-planes

// ---------------------------------------------------------------------------
// Kernel 1: pool each (b,t,c) plane 56x56 -> 8x8 (7x7 mean), add pos, write s.
// grid = 8192 (one block per plane, plane index p = (b*16+t)*64 + c), block=256
// ---------------------------------------------------------------------------
__global__ __launch_bounds__(256) void pool_kernel(const float* __restrict__ x,
                                                   const float* __restrict__ pos,
                                                   float* __restrict__ s_ws) {
    __shared__ float plane[HW];
    const int p   = blockIdx.x;
    const int tid = threadIdx.x;

    const float4* xp = reinterpret_cast<const float4*>(x + (size_t)p * HW);
    float4* pl4 = reinterpret_cast<float4*>(plane);
    // 784 float4 staged by 256 threads
    #pragma unroll
    for (int k = 0; k < 3; k++) pl4[tid + k * 256] = xp[tid + k * 256];
    if (tid < 16) pl4[768 + tid] = xp[768 + tid];
    __syncthreads();

    if (tid < 64) {
        const int i = tid >> 3, j = tid & 7;          // 8x8 output grid
        const float* base = plane + (i * 7) * 56 + j * 7;
        float sum = 0.f;
        #pragma unroll
        for (int r = 0; r < 7; r++) {
            #pragma unroll
            for (int cc = 0; cc < 7; cc++) sum += base[r * 56 + cc];
        }
        const int c = p & 63, t = (p >> 6) & 15, b = p >> 10;
        const int bc = b * 64 + c;
        const int off = ((bc << 4) + t) * 64 + tid;   // s layout (bc, t, 64)
        s_ws[off] = sum * (1.0f / 49.0f) + pos[off];
    }
}

// ---------------------------------------------------------------------------
// Kernel 2: per bc: LayerNorm(s) -> qk = s @ W -> dots -> softmax -> attn + I
// grid = 512, block = 64 (single wave)
// ---------------------------------------------------------------------------
__global__ __launch_bounds__(64) void attn_kernel(const float* __restrict__ s_ws,
                                                  const float* __restrict__ W,
                                                  const float* __restrict__ gamma,
                                                  const float* __restrict__ beta,
                                                  float* __restrict__ attn_ws) {
    __shared__ float w_lds[64 * 128];   // 32 KB
    __shared__ float s_lds[16 * 64];
    __shared__ float q_lds[16 * 65];    // +1 pad: conflict-free dots reads
    __shared__ float k_lds[16 * 65];
    __shared__ float d_lds[256];

    const int bc   = blockIdx.x;
    const int lane = threadIdx.x;

    // stage W (2048 float4, 32/lane) and s (256 float4, 4/lane)
    const float4* W4 = reinterpret_cast<const float4*>(W);
    float4* w4 = reinterpret_cast<float4*>(w_lds);
    #pragma unroll
    for (int k = 0; k < 32; k++) w4[lane + k * 64] = W4[lane + k * 64];
    const float4* S4 = reinterpret_cast<const float4*>(s_ws + (size_t)bc * 1024);
    float4* s4 = reinterpret_cast<float4*>(s_lds);
    #pragma unroll
    for (int k = 0; k < 4; k++) s4[lane + k * 64] = S4[lane + k * 64];
    const float g   = gamma[lane];
    const float bta = beta[lane];
    __syncthreads();

    // LayerNorm each of 16 rows; lane holds element `lane` of the row
    for (int r = 0; r < 16; r++) {
        float v = s_lds[r * 64 + lane];
        float sum = v, sq = v * v;
        #pragma unroll
        for (int off = 32; off > 0; off >>= 1) {
            sum += __shfl_xor(sum, off, 64);
            sq  += __shfl_xor(sq,  off, 64);
        }
        const float mu  = sum * (1.0f / 64.0f);
        const float var = sq * (1.0f / 64.0f) - mu * mu;
        s_lds[r * 64 + lane] = (v - mu) * rsqrtf(var + 1e-5f) * g + bta;
    }
    __syncthreads();

    // qk = s @ W : lane computes q[r][lane], k[r][lane]
    for (int r = 0; r < 16; r++) {
        float q = 0.f, kk = 0.f;
        #pragma unroll
        for (int d = 0; d < 64; d++) {
            const float sv = s_lds[r * 64 + d];            // broadcast
            q  += sv * w_lds[d * 128 + lane];              // bank = lane%32
            kk += sv * w_lds[d * 128 + 64 + lane];
        }
        q_lds[r * 65 + lane] = q;
        k_lds[r * 65 + lane] = kk;
    }
    __syncthreads();

    // dots[i][j] = 0.125 * q[i].k[j]; lane -> i = lane>>2, j = jj*4 + (lane&3)
    const int i = lane >> 2, j0 = lane & 3;
    #pragma unroll
    for (int jj = 0; jj < 4; jj++) {
        const int j = jj * 4 + j0;
        float acc = 0.f;
        #pragma unroll
        for (int d = 0; d < 64; d++)
            acc += q_lds[i * 65 + d] * k_lds[j * 65 + d];
        d_lds[i * 16 + j] = acc * 0.125f;
    }
    __syncthreads();

    // softmax per row + identity
    if (lane < 16) {
        float m = -1e30f;
        #pragma unroll
        for (int j = 0; j < 16; j++) m = fmaxf(m, d_lds[lane * 16 + j]);
        float e[16];
        float ssum = 0.f;
        #pragma unroll
        for (int j = 0; j < 16; j++) { e[j] = __expf(d_lds[lane * 16 + j] - m); ssum += e[j]; }
        const float inv = 1.0f / ssum;
        #pragma unroll
        for (int j = 0; j < 16; j++)
            d_lds[lane * 16 + j] = e[j] * inv + (j == lane ? 1.0f : 0.0f);
    }
    __syncthreads();

    #pragma unroll
    for (int k = 0; k < 4; k++)
        attn_ws[bc * 256 + k * 64 + lane] = d_lds[k * 64 + lane];
}

// ---------------------------------------------------------------------------
// Kernel 3: out planes = (attn + I) @ x planes, per (b,c).
// grid = (512, 2), block = 256; each thread handles float4 chunks of f.
// ---------------------------------------------------------------------------
__global__ __launch_bounds__(256) void apply_kernel(const float* __restrict__ x,
                                                    const float* __restrict__ attn_ws,
                                                    float* __restrict__ out) {
    __shared__ float A[256];   // (attn + I)[16][16]
    const int bc   = blockIdx.x;
    const int half = blockIdx.y;
    const int tid  = threadIdx.x;

    A[tid] = attn_ws[bc * 256 + tid];
    __syncthreads();

    const int b = bc >> 6, c = bc & 63;
    const float4* x4 = reinterpret_cast<const float4*>(x);
    float4* o4 = reinterpret_cast<float4*>(out);
    const size_t plane0 = ((size_t)b * 16 * 64 + c) * HW4;   // float4 index of (b,0,c)

    #pragma unroll
    for (int k = 0; k < 2; k++) {
        const int rem = 392 - k * 256;        // half covers 392 float4
        if (tid < rem) {
            const size_t f4 = (size_t)half * 392 + k * 256 + tid;
            float4 xv[16];
            #pragma unroll
            for (int j = 0; j < 16; j++)
                xv[j] = x4[plane0 + (size_t)j * TSTRIDE4 + f4];
            #pragma unroll
            for (int t = 0; t < 16; t++) {
                float4 a; a.x = 0.f; a.y = 0.f; a.z = 0.f; a.w = 0.f;
                #pragma unroll
                for (int j = 0; j < 16; j++) {
                    const float w = A[t * 16 + j];   // wave-uniform broadcast
                    a.x += w * xv[j].x;
                    a.y += w * xv[j].y;
                    a.z += w * xv[j].z;
                    a.w += w * xv[j].w;
                }
                o4[plane0 + (size_t)t * TSTRIDE4 + f4] = a;
            }
        }
    }
}

extern "C" void kernel_launch(void* const* d_in, const int* in_sizes, int n_in,
                              void* d_out, int out_size, void* d_ws, size_t ws_size,
                              hipStream_t stream) {
    (void)in_sizes; (void)n_in; (void)out_size; (void)ws_size;
    const float* x     = (const float*)d_in[0];
    const float* pos   = (const float*)d_in[1];
    const float* W     = (const float*)d_in[2];
    const float* gamma = (const float*)d_in[3];
    const float* beta  = (const float*)d_in[4];
    float* out = (float*)d_out;

    float* s_ws    = (float*)d_ws;           // 512*16*64 = 524288 floats
    float* attn_ws = s_ws + 512 * 16 * 64;   // 512*256   = 131072 floats

    pool_kernel<<<8192, 256, 0, stream>>>(x, pos, s_ws);
    attn_kernel<<<512, 64, 0, stream>>>(s_ws, W, gamma, beta, attn_ws);
    apply_kernel<<<dim3(512, 2), 256, 0, stream>>>(x, attn_ws, out);
}

// Round 6
// 70.551 us; speedup vs baseline: 1.1185x; 1.1185x over previous
//
#include <hip/hip_runtime.h>
#include <hip/hip_bf16.h>
#include <math.h>

// Problem constants (from reference):
//   x: (b=8, t=16, c=64, h=56, w=56) f32   -> 25,690,112 elems
//   pos_embedding: (512, 16, 64) f32
//   W_qk: (64, 128) f32  (in, out) ; q = cols 0..63, k = cols 64..127
//   gamma, beta: (64,) f32
// out[b,t,c,f] = sum_j (softmax(q k^T * 0.125)[bc,t,j] + delta_tj) * x[b,j,c,f]
// where bc = b*64 + c, f = h*w = 3136.
//
// ws layout: s_ws = 512*16*64 floats (2 MB), attn_ws = 512*256 floats (0.5 MB)

#define HW 3136            // 56*56
#define HW4 784            // HW/4
#define TSTRIDE4 50176     // 64*784, float4 stride between t-planes

// ---------------------------------------------------------------------------
// Kernel 1: pool each (b,t,c) plane 56x56 -> 8x8 (7x7 mean), add pos, write s.
// grid = 8192 (one block per plane, p = (b*16+t)*64 + c), block = 256
// ---------------------------------------------------------------------------
__global__ __launch_bounds__(256) void pool_kernel(const float* __restrict__ x,
                                                   const float* __restrict__ pos,
                                                   float* __restrict__ s_ws) {
    __shared__ float plane[HW];
    const int p   = blockIdx.x;
    const int tid = threadIdx.x;

    const float4* xp = reinterpret_cast<const float4*>(x + (size_t)p * HW);
    float4* pl4 = reinterpret_cast<float4*>(plane);
    #pragma unroll
    for (int k = 0; k < 3; k++) pl4[tid + k * 256] = xp[tid + k * 256];
    if (tid < 16) pl4[768 + tid] = xp[768 + tid];
    __syncthreads();

    if (tid < 64) {
        const int i = tid >> 3, j = tid & 7;          // 8x8 output grid
        const float* base = plane + (i * 7) * 56 + j * 7;
        float sum = 0.f;
        #pragma unroll
        for (int r = 0; r < 7; r++) {
            #pragma unroll
            for (int cc = 0; cc < 7; cc++) sum += base[r * 56 + cc];
        }
        const int c = p & 63, t = (p >> 6) & 15, b = p >> 10;
        const int bc = b * 64 + c;
        const int off = ((bc << 4) + t) * 64 + tid;   // s layout (bc, t, 64)
        s_ws[off] = sum * (1.0f / 49.0f) + pos[off];
    }
}

// ---------------------------------------------------------------------------
// Kernel 2: per bc: LayerNorm(s) -> qk = s @ W -> dots -> softmax -> attn + I
// grid = 512, block = 64 (single wave).
// W columns held in registers (lane owns q-col `lane` and k-col `64+lane`);
// s-row values read via wave-uniform ds_read_b128 broadcasts.
// ---------------------------------------------------------------------------
__global__ __launch_bounds__(64) void attn_kernel(const float* __restrict__ s_ws,
                                                  const float* __restrict__ W,
                                                  const float* __restrict__ gamma,
                                                  const float* __restrict__ beta,
                                                  float* __restrict__ attn_ws) {
    __shared__ float s_lds[16 * 64];
    __shared__ float q_lds[16 * 65];    // +1 pad: conflict-free dots reads
    __shared__ float k_lds[16 * 65];
    __shared__ float d_lds[256];

    const int bc   = blockIdx.x;
    const int lane = threadIdx.x;

    // W columns -> registers. W[d*128 + lane] is a contiguous 256B wave read.
    float wq[64], wk[64];
    #pragma unroll
    for (int d = 0; d < 64; d++) {
        wq[d] = W[d * 128 + lane];
        wk[d] = W[d * 128 + 64 + lane];
    }

    // stage s (256 float4, 4/lane)
    const float4* S4 = reinterpret_cast<const float4*>(s_ws + (size_t)bc * 1024);
    float4* s4 = reinterpret_cast<float4*>(s_lds);
    #pragma unroll
    for (int k = 0; k < 4; k++) s4[lane + k * 64] = S4[lane + k * 64];
    const float g   = gamma[lane];
    const float bta = beta[lane];
    __syncthreads();

    // LayerNorm each of 16 rows; lane holds element `lane` of the row
    for (int r = 0; r < 16; r++) {
        float v = s_lds[r * 64 + lane];
        float sum = v, sq = v * v;
        #pragma unroll
        for (int off = 32; off > 0; off >>= 1) {
            sum += __shfl_xor(sum, off, 64);
            sq  += __shfl_xor(sq,  off, 64);
        }
        const float mu  = sum * (1.0f / 64.0f);
        const float var = sq * (1.0f / 64.0f) - mu * mu;
        s_lds[r * 64 + lane] = (v - mu) * rsqrtf(var + 1e-5f) * g + bta;
    }
    __syncthreads();

    // qk = s @ W : lane computes q[r][lane], k[r][lane].
    // s-row read as 16 uniform float4 broadcasts (no bank conflicts).
    for (int r = 0; r < 16; r++) {
        float q = 0.f, kk = 0.f;
        #pragma unroll
        for (int dd = 0; dd < 16; dd++) {
            const float4 sv = *reinterpret_cast<const float4*>(&s_lds[r * 64 + dd * 4]);
            q  += sv.x * wq[dd * 4 + 0] + sv.y * wq[dd * 4 + 1]
                + sv.z * wq[dd * 4 + 2] + sv.w * wq[dd * 4 + 3];
            kk += sv.x * wk[dd * 4 + 0] + sv.y * wk[dd * 4 + 1]
                + sv.z * wk[dd * 4 + 2] + sv.w * wk[dd * 4 + 3];
        }
        q_lds[r * 65 + lane] = q;
        k_lds[r * 65 + lane] = kk;
    }
    __syncthreads();

    // dots[i][j] = 0.125 * q[i].k[j]; lane -> i = lane>>2, j = jj*4 + (lane&3)
    const int i = lane >> 2, j0 = lane & 3;
    #pragma unroll
    for (int jj = 0; jj < 4; jj++) {
        const int j = jj * 4 + j0;
        float acc = 0.f;
        #pragma unroll
        for (int d = 0; d < 64; d++)
            acc += q_lds[i * 65 + d] * k_lds[j * 65 + d];
        d_lds[i * 16 + j] = acc * 0.125f;
    }
    __syncthreads();

    // softmax per row + identity
    if (lane < 16) {
        float m = -1e30f;
        #pragma unroll
        for (int j = 0; j < 16; j++) m = fmaxf(m, d_lds[lane * 16 + j]);
        float e[16];
        float ssum = 0.f;
        #pragma unroll
        for (int j = 0; j < 16; j++) { e[j] = __expf(d_lds[lane * 16 + j] - m); ssum += e[j]; }
        const float inv = 1.0f / ssum;
        #pragma unroll
        for (int j = 0; j < 16; j++)
            d_lds[lane * 16 + j] = e[j] * inv + (j == lane ? 1.0f : 0.0f);
    }
    __syncthreads();

    #pragma unroll
    for (int k = 0; k < 4; k++)
        attn_ws[bc * 256 + k * 64 + lane] = d_lds[k * 64 + lane];
}

// ---------------------------------------------------------------------------
// Kernel 3: out planes = (attn + I) @ x planes, per (b,c).
// grid = (512, 2), block = 256. A read directly from global with block-uniform
// addresses (compiler -> s_load, constant cache) — no LDS, no barrier.
// ---------------------------------------------------------------------------
__device__ __forceinline__ void acc4(float4& a, float w, const float4& v) {
    a.x += w * v.x; a.y += w * v.y; a.z += w * v.z; a.w += w * v.w;
}

__global__ __launch_bounds__(256) void apply_kernel(const float* __restrict__ x,
                                                    const float* __restrict__ attn_ws,
                                                    float* __restrict__ out) {
    const int bc   = blockIdx.x;
    const int half = blockIdx.y;
    const int tid  = threadIdx.x;
    const int b = bc >> 6, c = bc & 63;

    const float4* x4 = reinterpret_cast<const float4*>(x);
    float4* o4 = reinterpret_cast<float4*>(out);
    const float4* A4 = reinterpret_cast<const float4*>(attn_ws + (size_t)bc * 256);
    const size_t plane0 = ((size_t)b * 1024 + c) * HW4;   // float4 index of (b,0,c)

    #pragma unroll
    for (int k = 0; k < 2; k++) {
        const int rem = 392 - k * 256;        // half covers 392 float4
        if (tid < rem) {
            const size_t f4 = (size_t)half * 392 + k * 256 + tid;
            float4 xv[16];
            #pragma unroll
            for (int j = 0; j < 16; j++)
                xv[j] = x4[plane0 + (size_t)j * TSTRIDE4 + f4];
            #pragma unroll
            for (int t = 0; t < 16; t++) {
                float4 a; a.x = 0.f; a.y = 0.f; a.z = 0.f; a.w = 0.f;
                #pragma unroll
                for (int jj = 0; jj < 4; jj++) {
                    const float4 w4 = A4[t * 4 + jj];     // block-uniform
                    acc4(a, w4.x, xv[jj * 4 + 0]);
                    acc4(a, w4.y, xv[jj * 4 + 1]);
                    acc4(a, w4.z, xv[jj * 4 + 2]);
                    acc4(a, w4.w, xv[jj * 4 + 3]);
                }
                o4[plane0 + (size_t)t * TSTRIDE4 + f4] = a;
            }
        }
    }
}

extern "C" void kernel_launch(void* const* d_in, const int* in_sizes, int n_in,
                              void* d_out, int out_size, void* d_ws, size_t ws_size,
                              hipStream_t stream) {
    (void)in_sizes; (void)n_in; (void)out_size; (void)ws_size;
    const float* x     = (const float*)d_in[0];
    const float* pos   = (const float*)d_in[1];
    const float* W     = (const float*)d_in[2];
    const float* gamma = (const float*)d_in[3];
    const float* beta  = (const float*)d_in[4];
    float* out = (float*)d_out;

    float* s_ws    = (float*)d_ws;           // 512*16*64 = 524288 floats
    float* attn_ws = s_ws + 512 * 16 * 64;   // 512*256   = 131072 floats

    pool_kernel<<<8192, 256, 0, stream>>>(x, pos, s_ws);
    attn_kernel<<<512, 64, 0, stream>>>(s_ws, W, gamma, beta, attn_ws);
    apply_kernel<<<dim3(512, 2), 256, 0, stream>>>(x, attn_ws, out);
}